// Round 1
// baseline (2630.986 us; speedup 1.0000x reference)
//
#include <hip/hip_runtime.h>
#include <cstdint>
#include <cstddef>

#define DT_F 0.5f

// ---------------------------------------------------------------------------
// Detect whether edge_index is stored as int64 (reference dtype) or int32.
// If int32 data is reinterpreted as int64, the high word holds the next index
// (almost surely nonzero) -> value >= 2^32 >= n fails the range check.
__global__ void detect_i64(const long long* __restrict__ ei, int E, int n,
                           int* __restrict__ flag) {
    __shared__ int ok;
    if (threadIdx.x == 0) ok = 1;
    __syncthreads();
    int m = E < 2048 ? E : 2048;
    for (int i = threadIdx.x; i < m; i += blockDim.x) {
        long long v = ei[i];
        if (v < 0 || v >= (long long)n) ok = 0;  // benign race, all write 0
    }
    __syncthreads();
    if (threadIdx.x == 0) flag[0] = ok;
}

// Pack edge_index -> int32 src/dst arrays (12B/edge/step instead of 20B).
__global__ void pack_edges(const void* __restrict__ eiv, int E,
                           const int* __restrict__ flag,
                           int* __restrict__ src32, int* __restrict__ dst32) {
    int e = blockIdx.x * blockDim.x + threadIdx.x;
    if (e >= E) return;
    if (flag[0]) {
        const long long* ei = (const long long*)eiv;
        src32[e] = (int)ei[e];
        dst32[e] = (int)ei[(size_t)E + e];
    } else {
        const int* ei = (const int*)eiv;
        src32[e] = ei[e];
        dst32[e] = ei[(size_t)E + e];
    }
}

// ---------------------------------------------------------------------------
// Precompute: PM = node_feat @ W_msg[:64]   (the loop-invariant projection)
//             HC = node_feat @ W_self[:64] + b_h  (self part of HCONST)
// One wave per node; lane j owns feature j; W tiles staged in LDS.
__global__ void proj_kernel(const float* __restrict__ nf,
                            const float* __restrict__ Wm,   // (65,64) row-major
                            const float* __restrict__ Wsf,  // (65,64)
                            const float* __restrict__ bh,
                            float* __restrict__ PM, float* __restrict__ HC,
                            int n) {
    __shared__ float sWm[64 * 64];
    __shared__ float sWs[64 * 64];
    for (int i = threadIdx.x; i < 64 * 64; i += blockDim.x) {
        sWm[i] = Wm[i];   // rows 0..63 of the (65,64) matrix
        sWs[i] = Wsf[i];
    }
    __syncthreads();
    int wave = (blockIdx.x * blockDim.x + threadIdx.x) >> 6;
    int lane = threadIdx.x & 63;
    if (wave >= n) return;
    float nfj = nf[(size_t)wave * 64 + lane];
    float am = 0.f, as = 0.f;
#pragma unroll 8
    for (int k = 0; k < 64; ++k) {
        float v = __shfl(nfj, k);
        am = fmaf(v, sWm[k * 64 + lane], am);
        as = fmaf(v, sWs[k * 64 + lane], as);
    }
    PM[(size_t)wave * 64 + lane] = am;
    HC[(size_t)wave * 64 + lane] = as + bh[lane];
}

// Precompute: HC[dst] += ew * PM[src]  (AGG_const, hoisted out of the scan).
// One wave per edge; lane j handles feature j (conflict-free within wave).
__global__ void edge_wide(const int* __restrict__ src, const int* __restrict__ dst,
                          const float* __restrict__ ew,
                          const float* __restrict__ PM, float* __restrict__ HC,
                          int E) {
    int w = (blockIdx.x * blockDim.x + threadIdx.x) >> 6;
    int lane = threadIdx.x & 63;
    if (w >= E) return;
    int s = src[w], d = dst[w];
    float wgt = ew[w];
    atomicAdd(&HC[(size_t)d * 64 + lane], wgt * PM[(size_t)s * 64 + lane]);
}

// ---------------------------------------------------------------------------
// Per step: force_raw[d] = sum_e ew * I[src]   (scalar per edge)
__global__ void edge_force(const int* __restrict__ src, const int* __restrict__ dst,
                           const float* __restrict__ ew, const float* __restrict__ I,
                           float* __restrict__ force, int E) {
    int e = blockIdx.x * blockDim.x + threadIdx.x;
    if (e < E) atomicAdd(&force[dst[e]], ew[e] * I[src[e]]);
}

// Per step: h = relu(HC + force*wmL + I*wsL); beta/gamma = sigmoid(h.w + b);
// SIR update (R dropped: it never feeds back and isn't an output).
// One wave per node; lane j owns feature j; force self-zeroed for next step.
__global__ void node_step(const float* __restrict__ HC,
                          const float* __restrict__ Wm,   // row 64 = wmL
                          const float* __restrict__ Wsf,  // row 64 = wsL
                          const float* __restrict__ wb, const float* __restrict__ bb,
                          const float* __restrict__ wg, const float* __restrict__ bg,
                          float* __restrict__ force,
                          float* __restrict__ S, float* __restrict__ I,
                          float* __restrict__ Iseq_t,
                          float* __restrict__ beta_out, float* __restrict__ gamma_out,
                          int n) {
    int wave = (blockIdx.x * blockDim.x + threadIdx.x) >> 6;
    int lane = threadIdx.x & 63;
    if (wave >= n) return;
    float fr = force[wave];   // broadcast load (same address all lanes)
    float Iv = I[wave];
    float h = HC[(size_t)wave * 64 + lane]
            + fr * Wm[64 * 64 + lane]
            + Iv * Wsf[64 * 64 + lane];
    h = fmaxf(h, 0.f);
    float pb = h * wb[lane];
    float pg = h * wg[lane];
#pragma unroll
    for (int o = 32; o; o >>= 1) {
        pb += __shfl_xor(pb, o);
        pg += __shfl_xor(pg, o);
    }
    if (lane == 0) {
        float beta  = 1.f / (1.f + expf(-(pb + bb[0])));
        float gamma = 1.f / (1.f + expf(-(pg + bg[0])));
        float f   = fminf(fmaxf(fr, 0.f), 1000.f);
        float Sv  = S[wave];
        float inf_ = beta * Sv * f;
        float rec  = gamma * Iv;
        float Sn = Sv - inf_ * DT_F;          Sn = fminf(fmaxf(Sn, 0.f), 1.f);
        float In = Iv + (inf_ - rec) * DT_F;  In = fminf(fmaxf(In, 0.f), 1.f);
        S[wave] = Sn;
        I[wave] = In;
        Iseq_t[wave]    = In;
        beta_out[wave]  = beta;   // overwritten each step; last step survives
        gamma_out[wave] = gamma;
        force[wave] = 0.f;        // ready for next step's edge_force
    }
}

// ---------------------------------------------------------------------------
extern "C" void kernel_launch(void* const* d_in, const int* in_sizes, int n_in,
                              void* d_out, int out_size, void* d_ws, size_t ws_size,
                              hipStream_t stream) {
    const float* S0  = (const float*)d_in[0];
    const float* I0  = (const float*)d_in[1];
    const float* nf  = (const float*)d_in[4];
    const void*  ei  = d_in[5];
    const float* ew  = (const float*)d_in[6];
    const float* Wm  = (const float*)d_in[7];
    const float* Wsf = (const float*)d_in[8];
    const float* bh  = (const float*)d_in[9];
    const float* wb  = (const float*)d_in[10];
    const float* bb  = (const float*)d_in[11];
    const float* wg  = (const float*)d_in[12];
    const float* bg  = (const float*)d_in[13];

    const int n = in_sizes[0];
    const int T = in_sizes[3];
    const int E = in_sizes[6];

    char* ws = (char*)d_ws;
    size_t off = 0;
    auto alloc = [&](size_t bytes) {
        size_t p = off;
        off = (off + bytes + 255) & ~(size_t)255;
        return p;
    };
    float* HC    = (float*)(ws + alloc((size_t)n * 64 * 4));
    float* PM    = (float*)(ws + alloc((size_t)n * 64 * 4));
    float* force = (float*)(ws + alloc((size_t)n * 4));
    float* S     = (float*)(ws + alloc((size_t)n * 4));
    float* I     = (float*)(ws + alloc((size_t)n * 4));
    int* src32   = (int*)(ws + alloc((size_t)E * 4));
    int* dst32   = (int*)(ws + alloc((size_t)E * 4));
    int* flag    = (int*)(ws + alloc(256));
    if (off > ws_size) return;  // workspace too small: fail loudly (poisoned out)

    float* out       = (float*)d_out;
    float* beta_out  = out + (size_t)T * n;
    float* gamma_out = out + (size_t)T * n + n;

    // State init (fresh every launch — no cross-call state).
    hipMemcpyAsync(S, S0, (size_t)n * 4, hipMemcpyDeviceToDevice, stream);
    hipMemcpyAsync(I, I0, (size_t)n * 4, hipMemcpyDeviceToDevice, stream);
    hipMemsetAsync(force, 0, (size_t)n * 4, stream);

    // One-time precompute (per launch): pack edges, project, hoisted scatter.
    detect_i64<<<1, 256, 0, stream>>>((const long long*)ei, E, n, flag);
    pack_edges<<<(E + 255) / 256, 256, 0, stream>>>(ei, E, flag, src32, dst32);
    proj_kernel<<<(n * 64 + 255) / 256, 256, 0, stream>>>(nf, Wm, Wsf, bh, PM, HC, n);
    edge_wide<<<(E * 64 + 255) / 256, 256, 0, stream>>>(src32, dst32, ew, PM, HC, E);

    // 20-step scan: scalar edge scatter + fused node update per step.
    for (int t = 0; t < T; ++t) {
        edge_force<<<(E + 255) / 256, 256, 0, stream>>>(src32, dst32, ew, I, force, E);
        node_step<<<(n * 64 + 255) / 256, 256, 0, stream>>>(
            HC, Wm, Wsf, wb, bb, wg, bg, force, S, I,
            out + (size_t)t * n, beta_out, gamma_out, n);
    }
}

// Round 5
// 1093.246 us; speedup vs baseline: 2.4066x; 2.4066x over previous
//
#include <hip/hip_runtime.h>
#include <cstdint>
#include <cstddef>

#define DT_F 0.5f

// ---------------------------------------------------------------------------
// edge_index dtype detection (reference says int64; harness doc says int).
// int32 data read as int64 yields values with a nonzero high word -> >= n.
__global__ void detect_i64(const long long* __restrict__ ei, int E, int n,
                           int* __restrict__ flag) {
    __shared__ int ok;
    if (threadIdx.x == 0) ok = 1;
    __syncthreads();
    int m = E < 2048 ? E : 2048;
    for (int i = threadIdx.x; i < m; i += blockDim.x) {
        long long v = ei[i];
        if (v < 0 || v >= (long long)n) ok = 0;  // benign race, all write 0
    }
    __syncthreads();
    if (threadIdx.x == 0) flag[0] = ok;
}

__device__ __forceinline__ int ld_idx(const void* ei, size_t pos, int w64) {
    return w64 ? (int)((const long long*)ei)[pos] : ((const int*)ei)[pos];
}

// ---------------------------------------------------------------------------
// CSR build: in-degree histogram -> exclusive scan -> atomic-cursor fill.
__global__ void k_count(const void* __restrict__ ei, const int* __restrict__ flag,
                        int E, int* __restrict__ cnt) {
    int e = blockIdx.x * blockDim.x + threadIdx.x;
    if (e >= E) return;
    int d = ld_idx(ei, (size_t)E + e, flag[0]);
    atomicAdd(&cnt[d], 1);
}

#define SCAN_B 1024
__global__ void k_scan1(const int* __restrict__ cnt, int* __restrict__ part,
                        int* __restrict__ bsum, int n) {
    __shared__ int sh[SCAN_B];
    int t = threadIdx.x;
    int g = blockIdx.x * SCAN_B + t;
    int v = g < n ? cnt[g] : 0;
    sh[t] = v;
    __syncthreads();
    for (int o = 1; o < SCAN_B; o <<= 1) {
        int x = t >= o ? sh[t - o] : 0;
        __syncthreads();
        sh[t] += x;
        __syncthreads();
    }
    if (g < n) part[g] = sh[t] - v;              // exclusive
    if (t == SCAN_B - 1) bsum[blockIdx.x] = sh[t];  // block total
}

__global__ void k_scan2(int* __restrict__ bsum, int nb) {  // nb <= 1024
    __shared__ int sh[SCAN_B];
    int t = threadIdx.x;
    int v = t < nb ? bsum[t] : 0;
    sh[t] = v;
    __syncthreads();
    for (int o = 1; o < SCAN_B; o <<= 1) {
        int x = t >= o ? sh[t - o] : 0;
        __syncthreads();
        sh[t] += x;
        __syncthreads();
    }
    if (t < nb) bsum[t] = sh[t] - v;             // exclusive
}

__global__ void k_scan3(const int* __restrict__ part, const int* __restrict__ bsum,
                        int* __restrict__ rowptr, int n, int E) {
    int g = blockIdx.x * SCAN_B + threadIdx.x;
    if (g < n) rowptr[g] = part[g] + bsum[blockIdx.x];
    if (g == 0) rowptr[n] = E;
}

__global__ void k_fill(const void* __restrict__ ei, const float* __restrict__ ew,
                       const int* __restrict__ flag, int E,
                       int* __restrict__ cursor,
                       int* __restrict__ cols, float* __restrict__ vals) {
    int e = blockIdx.x * blockDim.x + threadIdx.x;
    if (e >= E) return;
    int w64 = flag[0];
    int s = ld_idx(ei, e, w64);
    int d = ld_idx(ei, (size_t)E + e, w64);
    int p = atomicAdd(&cursor[d], 1);
    cols[p] = s;
    vals[p] = ew[e];
}

// ---------------------------------------------------------------------------
// Precompute: PM = nf @ W_msg[:64];  HC = nf @ W_self[:64] + b_h.
// One wave per node; lane j owns feature j; W tiles staged in LDS.
__global__ void proj_kernel(const float* __restrict__ nf,
                            const float* __restrict__ Wm,   // (65,64) row-major
                            const float* __restrict__ Wsf,  // (65,64)
                            const float* __restrict__ bh,
                            float* __restrict__ PM, float* __restrict__ HC,
                            int n) {
    __shared__ float sWm[64 * 64];
    __shared__ float sWs[64 * 64];
    for (int i = threadIdx.x; i < 64 * 64; i += blockDim.x) {
        sWm[i] = Wm[i];
        sWs[i] = Wsf[i];
    }
    __syncthreads();
    int wave = (blockIdx.x * blockDim.x + threadIdx.x) >> 6;
    int lane = threadIdx.x & 63;
    if (wave >= n) return;
    float nfj = nf[(size_t)wave * 64 + lane];
    float am = 0.f, as = 0.f;
#pragma unroll 8
    for (int k = 0; k < 64; ++k) {
        float v = __shfl(nfj, k);
        am = fmaf(v, sWm[k * 64 + lane], am);
        as = fmaf(v, sWs[k * 64 + lane], as);
    }
    PM[(size_t)wave * 64 + lane] = am;
    HC[(size_t)wave * 64 + lane] = as + bh[lane];
}

// Hoisted constant aggregation, CSR form (no atomics):
// HC[d] += sum_{e in in-edges(d)} ew_e * PM[src_e]
__global__ void edge_wide_csr(const int* __restrict__ rowptr,
                              const int* __restrict__ cols,
                              const float* __restrict__ vals,
                              const float* __restrict__ PM,
                              float* __restrict__ HC, int n) {
    int wave = (blockIdx.x * blockDim.x + threadIdx.x) >> 6;
    int lane = threadIdx.x & 63;
    if (wave >= n) return;
    int r0 = rowptr[wave], r1 = rowptr[wave + 1];
    float acc = 0.f;
    for (int e = r0; e < r1; ++e) {
        int s = cols[e];            // wave-uniform broadcast load
        float w = vals[e];
        acc = fmaf(w, PM[(size_t)s * 64 + lane], acc);  // coalesced 256B row
    }
    size_t o = (size_t)wave * 64 + lane;
    HC[o] += acc;
}

// ---------------------------------------------------------------------------
// Fused per-step kernel: force (CSR sum, in registers) + h + beta/gamma + SIR.
// One wave per node; I double-buffered; S updated in place (own node only).
__global__ void step_fused(const int* __restrict__ rowptr,
                           const int* __restrict__ cols,
                           const float* __restrict__ vals,
                           const float* __restrict__ HC,
                           const float* __restrict__ wmL,  // W_msg row 64
                           const float* __restrict__ wsL,  // W_self row 64
                           const float* __restrict__ wb, const float* __restrict__ bb,
                           const float* __restrict__ wg, const float* __restrict__ bg,
                           const float* __restrict__ I_old, float* __restrict__ I_new,
                           float* __restrict__ S,
                           float* __restrict__ Iseq_t,
                           float* __restrict__ beta_out, float* __restrict__ gamma_out,
                           int n, int last) {
    int wave = (blockIdx.x * blockDim.x + threadIdx.x) >> 6;
    int lane = threadIdx.x & 63;
    if (wave >= n) return;
    int r0 = rowptr[wave], r1 = rowptr[wave + 1];
    float f = 0.f;
    for (int e = r0 + lane; e < r1; e += 64)
        f = fmaf(vals[e], I_old[cols[e]], f);
#pragma unroll
    for (int o = 32; o; o >>= 1) f += __shfl_xor(f, o);   // all lanes get force
    float Iv = I_old[wave];                               // broadcast load
    float h = HC[(size_t)wave * 64 + lane] + f * wmL[lane] + Iv * wsL[lane];
    h = fmaxf(h, 0.f);
    float pb = h * wb[lane];
    float pg = h * wg[lane];
#pragma unroll
    for (int o = 32; o; o >>= 1) {
        pb += __shfl_xor(pb, o);
        pg += __shfl_xor(pg, o);
    }
    if (lane == 0) {
        float beta  = 1.f / (1.f + expf(-(pb + bb[0])));
        float gamma = 1.f / (1.f + expf(-(pg + bg[0])));
        float fc = fminf(fmaxf(f, 0.f), 1000.f);
        float Sv = S[wave];
        float inf_ = beta * Sv * fc;
        float rec  = gamma * Iv;
        float Sn = fminf(fmaxf(Sv - inf_ * DT_F, 0.f), 1.f);
        float In = fminf(fmaxf(Iv + (inf_ - rec) * DT_F, 0.f), 1.f);
        S[wave] = Sn;
        I_new[wave] = In;
        Iseq_t[wave] = In;
        if (last) { beta_out[wave] = beta; gamma_out[wave] = gamma; }
    }
}

// ---------------------------------------------------------------------------
extern "C" void kernel_launch(void* const* d_in, const int* in_sizes, int n_in,
                              void* d_out, int out_size, void* d_ws, size_t ws_size,
                              hipStream_t stream) {
    const float* S0  = (const float*)d_in[0];
    const float* I0  = (const float*)d_in[1];
    const float* nf  = (const float*)d_in[4];
    const void*  ei  = d_in[5];
    const float* ew  = (const float*)d_in[6];
    const float* Wm  = (const float*)d_in[7];
    const float* Wsf = (const float*)d_in[8];
    const float* bh  = (const float*)d_in[9];
    const float* wb  = (const float*)d_in[10];
    const float* bb  = (const float*)d_in[11];
    const float* wg  = (const float*)d_in[12];
    const float* bg  = (const float*)d_in[13];

    const int n = in_sizes[0];
    const int T = in_sizes[3];
    const int E = in_sizes[6];
    const int nb = (n + SCAN_B - 1) / SCAN_B;   // scan blocks (<=1024 assumed)

    char* ws = (char*)d_ws;
    size_t off = 0;
    auto alloc = [&](size_t bytes) {
        size_t p = off;
        off = (off + bytes + 255) & ~(size_t)255;
        return p;
    };
    float* HC     = (float*)(ws + alloc((size_t)n * 64 * 4));
    float* PM     = (float*)(ws + alloc((size_t)n * 64 * 4));
    float* S      = (float*)(ws + alloc((size_t)n * 4));
    float* Ib0    = (float*)(ws + alloc((size_t)n * 4));
    float* Ib1    = (float*)(ws + alloc((size_t)n * 4));
    int*   cnt    = (int*)(ws + alloc((size_t)n * 4));
    int*   part   = (int*)(ws + alloc((size_t)n * 4));
    int*   bsum   = (int*)(ws + alloc((size_t)SCAN_B * 4));
    int*   rowptr = (int*)(ws + alloc((size_t)(n + 1) * 4));
    int*   cursor = (int*)(ws + alloc((size_t)(n + 1) * 4));
    int*   cols   = (int*)(ws + alloc((size_t)E * 4));
    float* vals   = (float*)(ws + alloc((size_t)E * 4));
    int*   flag   = (int*)(ws + alloc(256));
    if (off > ws_size) return;  // workspace too small: fail loudly (poisoned out)

    float* out       = (float*)d_out;
    float* beta_out  = out + (size_t)T * n;
    float* gamma_out = out + (size_t)T * n + n;

    // State init (fresh every launch — no cross-call state).
    hipMemcpyAsync(S,   S0, (size_t)n * 4, hipMemcpyDeviceToDevice, stream);
    hipMemcpyAsync(Ib0, I0, (size_t)n * 4, hipMemcpyDeviceToDevice, stream);
    hipMemsetAsync(cnt, 0, (size_t)n * 4, stream);

    // CSR build (sorted by dst).
    detect_i64<<<1, 256, 0, stream>>>((const long long*)ei, E, n, flag);
    k_count<<<(E + 255) / 256, 256, 0, stream>>>(ei, flag, E, cnt);
    k_scan1<<<nb, SCAN_B, 0, stream>>>(cnt, part, bsum, n);
    k_scan2<<<1, SCAN_B, 0, stream>>>(bsum, nb);
    k_scan3<<<nb, SCAN_B, 0, stream>>>(part, bsum, rowptr, n, E);
    hipMemcpyAsync(cursor, rowptr, (size_t)n * 4, hipMemcpyDeviceToDevice, stream);
    k_fill<<<(E + 255) / 256, 256, 0, stream>>>(ei, ew, flag, E, cursor, cols, vals);

    // Loop-invariant precompute.
    proj_kernel<<<(n * 64 + 255) / 256, 256, 0, stream>>>(nf, Wm, Wsf, bh, PM, HC, n);
    edge_wide_csr<<<(n * 64 + 255) / 256, 256, 0, stream>>>(rowptr, cols, vals, PM, HC, n);

    // 20-step scan: ONE fused kernel per step, no atomics, force in registers.
    const float* wmL = Wm  + 64 * 64;
    const float* wsL = Wsf + 64 * 64;
    for (int t = 0; t < T; ++t) {
        const float* Iold = (t & 1) ? Ib1 : Ib0;
        float*       Inew = (t & 1) ? Ib0 : Ib1;
        step_fused<<<(n * 64 + 255) / 256, 256, 0, stream>>>(
            rowptr, cols, vals, HC, wmL, wsL, wb, bb, wg, bg,
            Iold, Inew, S, out + (size_t)t * n, beta_out, gamma_out,
            n, t == T - 1 ? 1 : 0);
    }
}